// Round 4
// baseline (6877.202 us; speedup 1.0000x reference)
//
#include <hip/hip_runtime.h>
#include <hip/hip_bf16.h>

#define BATCH 1024
#define HD 256
#define MLEN 80
#define LPRE 60
#define LFWD 80
#define KIN 32
#define KOUT 16

typedef unsigned short bf16_t;
typedef __attribute__((ext_vector_type(8))) short bf16x8;
typedef __attribute__((ext_vector_type(4))) float f32x4;

__device__ __forceinline__ float bf2f(bf16_t v){ return __uint_as_float(((unsigned)v)<<16); }
__device__ __forceinline__ bf16_t f2bf(float f){
    unsigned u = __float_as_uint(f);
    return (bf16_t)((u + 0x7FFFu + ((u>>16)&1u)) >> 16);
}
__device__ __forceinline__ unsigned pack2(float lo, float hi){
    return (unsigned)f2bf(lo) | ((unsigned)f2bf(hi)<<16);
}
__device__ __forceinline__ float sigm(float x){ return 1.0f/(1.0f+__expf(-x)); }

// GRU pack group byte offsets: r:[0) z:[256K) in:[512K) hn:[640K)
#define OFF_Z  262144
#define OFF_IN 524288
#define OFF_HN 655360

// ---------------------------------------------------------------------------
// Prep kernels — verbatim from R2 (which passed)
// ---------------------------------------------------------------------------
__global__ void pack_gru(const float* __restrict__ Wih, const float* __restrict__ Whh,
                         bf16_t* __restrict__ dst)
{
    int T = blockIdx.x*256 + threadIdx.x;   // < 49152
    int grp, local;
    if (T < 16384){ grp=0; local=T; }
    else if (T < 32768){ grp=1; local=T-16384; }
    else if (T < 40960){ grp=2; local=T-32768; }
    else { grp=3; local=T-40960; }
    int nkt = (grp<2)?16:8;
    int nt  = local / (nkt*64);
    int rem = local - nt*(nkt*64);
    int kt  = rem >> 6;
    int l   = rem & 63;
    int n   = nt*16 + (l&15);
    int k0  = kt*32 + ((l>>4)<<3);
    unsigned w[4];
    #pragma unroll
    for (int h2=0; h2<4; h2++){
        float v[2];
        #pragma unroll
        for (int s=0; s<2; s++){
            int k = k0 + h2*2 + s;
            if (grp==0)      v[s] = (k<256)? Wih[(size_t)n*HD + k]       : Whh[(size_t)n*HD + (k-256)];
            else if (grp==1) v[s] = (k<256)? Wih[(size_t)(256+n)*HD + k] : Whh[(size_t)(256+n)*HD + (k-256)];
            else if (grp==2) v[s] = Wih[(size_t)(512+n)*HD + k];
            else             v[s] = Whh[(size_t)(512+n)*HD + k];
        }
        w[h2] = pack2(v[0], v[1]);
    }
    uint4 u = {w[0],w[1],w[2],w[3]};
    *(uint4*)((char*)dst + (size_t)T*16) = u;
}

__global__ void pack_B512(const float* __restrict__ W, bf16_t* __restrict__ dst)
{
    int T = blockIdx.x*256 + threadIdx.x;   // < 16384
    int nt = T >> 10, kt = (T>>6)&15, l = T&63;
    int n = nt*16 + (l&15);
    int k0 = kt*32 + ((l>>4)<<3);
    unsigned w[4];
    #pragma unroll
    for (int h2=0; h2<4; h2++)
        w[h2] = pack2(W[(size_t)n*512 + k0+h2*2], W[(size_t)n*512 + k0+h2*2+1]);
    uint4 u = {w[0],w[1],w[2],w[3]};
    *(uint4*)((char*)dst + (size_t)T*16) = u;
}

__global__ void wfuse_kernel(const float* __restrict__ dembW, const float* __restrict__ dembB,
                             const float* __restrict__ outW, const float* __restrict__ outB,
                             float* __restrict__ Wfuse, float* __restrict__ ebias)
{
    int T = blockIdx.x*256 + threadIdx.x;
    if (T < 65536){
        int k = T >> 8, n = T & 255;
        float acc = 0.f;
        #pragma unroll
        for (int o=0;o<16;o++) acc += dembW[(size_t)n*48 + o]*outW[(size_t)o*HD + k];
        Wfuse[(size_t)k*HD + n] = acc;
    } else if (T < 65792){
        int n = T - 65536;
        float acc = dembB[n];
        #pragma unroll
        for (int o=0;o<16;o++) acc += outB[o]*dembW[(size_t)n*48 + o];
        ebias[n] = acc;
    }
}

__global__ void pack_e(const float* __restrict__ Wfuse, const float* __restrict__ dembW,
                       bf16_t* __restrict__ dst)
{
    int T = blockIdx.x*256 + threadIdx.x;   // < 9216
    int nt = T/576, rem = T - nt*576;
    int kt = rem >> 6, l = rem & 63;
    int n = nt*16 + (l&15);
    int k0 = kt*32 + ((l>>4)<<3);
    unsigned w[4];
    #pragma unroll
    for (int h2=0; h2<4; h2++){
        float v[2];
        #pragma unroll
        for (int s=0;s<2;s++){
            int k = k0 + h2*2 + s;
            v[s] = (kt<8)? Wfuse[(size_t)k*HD + n] : dembW[(size_t)n*48 + 16 + (k-256)];
        }
        w[h2] = pack2(v[0], v[1]);
    }
    uint4 u = {w[0],w[1],w[2],w[3]};
    *(uint4*)((char*)dst + (size_t)T*16) = u;
}

__global__ void pack_logits(const float* __restrict__ Wfuse, const float* __restrict__ dembW,
                            const float* __restrict__ attW, const float* __restrict__ attB,
                            const float* __restrict__ dembB, const float* __restrict__ ebias,
                            bf16_t* __restrict__ BL, bf16_t* __restrict__ BL0,
                            float* __restrict__ lb, float* __restrict__ lb0)
{
    int T = blockIdx.x*256 + threadIdx.x;
    if (T < 5760){
        int variant = (T < 2880) ? 0 : 1;
        int local = variant ? (T-2880) : T;
        int nt = local/576, rem = local - nt*576;
        int kt = rem >> 6, l = rem & 63;
        int m  = nt*16 + (l&15);
        int k0 = kt*32 + ((l>>4)<<3);
        unsigned w[4];
        #pragma unroll
        for (int h2=0; h2<4; h2++){
            float v[2];
            for (int s=0;s<2;s++){
                int k = k0 + h2*2 + s;
                float acc;
                if (kt < 8){
                    if (variant == 0){
                        acc = attW[(size_t)m*512 + 256 + k];
                        for (int n=0;n<256;n++) acc += Wfuse[(size_t)k*HD + n]*attW[(size_t)m*512 + n];
                    } else {
                        acc = attW[(size_t)m*512 + 256 + k];
                    }
                } else {
                    int kp = k - 256;
                    acc = 0.f;
                    for (int n=0;n<256;n++) acc += dembW[(size_t)n*48 + 16 + kp]*attW[(size_t)m*512 + n];
                }
                v[s] = acc;
            }
            w[h2] = pack2(v[0], v[1]);
        }
        uint4 u = {w[0],w[1],w[2],w[3]};
        bf16_t* d = variant ? BL0 : BL;
        *(uint4*)((char*)d + (size_t)local*16) = u;
    } else if (T < 5840){
        int m = T - 5760;
        float acc = attB[m];
        for (int n=0;n<256;n++) acc += ebias[n]*attW[(size_t)m*512 + n];
        lb[m] = acc;
    } else if (T < 5920){
        int m = T - 5840;
        float acc = attB[m];
        for (int n=0;n<256;n++) acc += dembB[n]*attW[(size_t)m*512 + n];
        lb0[m] = acc;
    }
}

// encoder embeddings -> [t][B][H] bf16 global layout (R2 verbatim). grid (64,60)
__global__ __launch_bounds__(256) void emb_kernel(
    const float* __restrict__ px, const float* __restrict__ py,
    const float* __restrict__ embW, const float* __restrict__ embB,
    bf16_t* __restrict__ emb)
{
    __shared__ float Ws[256*49];
    __shared__ float xy[16][48];
    __shared__ float bs[256];
    int t = blockIdx.y, b0 = blockIdx.x*16, tid = threadIdx.x;
    for (int i = tid; i < 256*48; i += 256){ int n=i/48, k=i-n*48; Ws[n*49+k]=embW[i]; }
    bs[tid] = embB[tid];
    for (int i = tid; i < 16*48; i += 256){
        int r=i/48, k=i-r*48;
        xy[r][k] = (k<KIN)? px[((size_t)t*BATCH + b0+r)*KIN + k]
                          : py[((size_t)t*BATCH + b0+r)*KOUT + (k-KIN)];
    }
    __syncthreads();
    int n = tid;
    const float* w = &Ws[n*49];
    for (int r=0;r<16;r++){
        float acc = bs[n];
        #pragma unroll
        for (int k=0;k<48;k++) acc += xy[r][k]*w[k];
        emb[((size_t)t*BATCH + b0+r)*HD + n] = f2bf(acc);
    }
}

__global__ void fxconv(const float* __restrict__ fx, bf16_t* __restrict__ dst)
{
    size_t i = (size_t)blockIdx.x*256 + threadIdx.x;
    const float4* s = (const float4*)(fx + i*8);
    float4 a = s[0], b = s[1];
    uint4 u = { pack2(a.x,a.y), pack2(a.z,a.w), pack2(b.x,b.y), pack2(b.z,b.w) };
    *(uint4*)(dst + i*8) = u;
}

// ---------------------------------------------------------------------------
// GRU phase — R2 gru_step body, transliterated for 512 threads / 8 waves.
// Stages [A0|A1] into As, computes all 16 column tiles, writes HF', HB',
// extra (enc_out tile or h-hist tile). Trailing barrier.
// ---------------------------------------------------------------------------
__device__ __forceinline__ void gru_phase(
    int tid, int b0,
    const bf16_t* __restrict__ A0, const bf16_t* __restrict__ A1,
    const bf16_t* __restrict__ Bp,
    const float* __restrict__ bih, const float* __restrict__ bhh,
    const float* __restrict__ hprev, float* __restrict__ hnext,
    bf16_t* __restrict__ hnext_bf, bf16_t* __restrict__ extra_bf,
    bf16_t (*As)[520])
{
    for (int i = tid; i < 1024; i += 512){
        int r = i>>6, c = i&63;
        const bf16_t* src = (c<32)? (A0 + (size_t)(b0+r)*HD + c*8)
                                  : (A1 + (size_t)(b0+r)*HD + (c-32)*8);
        *(uint4*)&As[r][c*8] = *(const uint4*)src;
    }
    __syncthreads();
    int lane = tid & 63, wave = tid >> 6;
    const char* arow = (const char*)&As[lane&15][(lane>>4)*8];
    const char* bpc = (const char*)Bp;
    size_t loff = (size_t)lane*16;
    #pragma unroll
    for (int half=0; half<2; half++){
        int jt = wave + 8*half;
        f32x4 cr={0,0,0,0}, cz={0,0,0,0}, ci={0,0,0,0}, ch={0,0,0,0};
        #pragma unroll
        for (int kt=0; kt<16; kt++){
            bf16x8 a  = *(const bf16x8*)(arow + kt*64);
            bf16x8 br = *(const bf16x8*)(bpc + (size_t)(((jt<<4)+kt)<<10) + loff);
            bf16x8 bz = *(const bf16x8*)(bpc + OFF_Z + (size_t)(((jt<<4)+kt)<<10) + loff);
            cr = __builtin_amdgcn_mfma_f32_16x16x32_bf16(a, br, cr, 0,0,0);
            cz = __builtin_amdgcn_mfma_f32_16x16x32_bf16(a, bz, cz, 0,0,0);
            if (kt < 8){
                bf16x8 bi = *(const bf16x8*)(bpc + OFF_IN + (size_t)(((jt<<3)+kt)<<10) + loff);
                ci = __builtin_amdgcn_mfma_f32_16x16x32_bf16(a, bi, ci, 0,0,0);
            } else {
                bf16x8 bh = *(const bf16x8*)(bpc + OFF_HN + (size_t)(((jt<<3)+kt-8)<<10) + loff);
                ch = __builtin_amdgcn_mfma_f32_16x16x32_bf16(a, bh, ch, 0,0,0);
            }
        }
        int j = (jt<<4) + (lane&15);
        float b_r = bih[j] + bhh[j];
        float b_z = bih[256+j] + bhh[256+j];
        float b_i = bih[512+j], b_h = bhh[512+j];
        #pragma unroll
        for (int q=0;q<4;q++){
            int b = b0 + ((lane>>4)<<2) + q;
            float rv = sigm(cr[q] + b_r);
            float zv = sigm(cz[q] + b_z);
            float nv = tanhf(ci[q] + b_i + rv*(ch[q] + b_h));
            float h2 = (1.0f - zv)*nv + zv*hprev[(size_t)b*HD + j];
            hnext[(size_t)b*HD + j] = h2;
            bf16_t hb = f2bf(h2);
            hnext_bf[(size_t)b*HD + j] = hb;
            extra_bf[(size_t)b*HD + j] = hb;
        }
    }
    __syncthreads();
}

// ---------------------------------------------------------------------------
// Persistent kernel: 64 blocks x 512 threads; block owns 16 batch rows.
// Dataflow and per-phase math identical to R2's five kernels; kernel
// boundaries replaced by __syncthreads. All intermediates in global
// per-block-private slices (same-CU RAW through L2 after barrier).
// ---------------------------------------------------------------------------
__global__ __launch_bounds__(512) void seq_kernel(
    const bf16_t* __restrict__ FXB,
    const bf16_t* __restrict__ PENC, const bf16_t* __restrict__ PDEC,
    const bf16_t* __restrict__ PCMB, const bf16_t* __restrict__ PE,
    const bf16_t* __restrict__ PBL, const bf16_t* __restrict__ PBL0,
    const float* __restrict__ ebih, const float* __restrict__ ebhh,
    const float* __restrict__ dbih, const float* __restrict__ dbhh,
    const float* __restrict__ EBIAS, const float* __restrict__ DEMBB,
    const float* __restrict__ LBg, const float* __restrict__ LB0g,
    const float* __restrict__ CBg,
    bf16_t* __restrict__ HIST,      // [80][B][H]: emb in tiles 0..59, then h-hist 0..79
    bf16_t* __restrict__ ENC_OUT,   // [60][B][H]
    float* __restrict__ HF0, float* __restrict__ HF1,
    bf16_t* __restrict__ HB0, bf16_t* __restrict__ HB1,
    bf16_t* __restrict__ EBUF, bf16_t* __restrict__ CTXB, bf16_t* __restrict__ GBUF)
{
    __shared__ __align__(16) bf16_t As[16][520];
    __shared__ float lg[16][84];
    __shared__ float red[16][17];
    __shared__ float rmax[16], rsum[16];
    __shared__ float awl[16][64];

    int tid = threadIdx.x;
    int lane = tid & 63, wave = tid >> 6;
    int b0 = blockIdx.x*16;
    size_t loff = (size_t)lane*16;

    float* HF[2] = {HF0, HF1};
    bf16_t* HB[2] = {HB0, HB1};
    int p = 0;

    // =================== encoder (R2 gru_step x60) ===================
    for (int t = 0; t < LPRE; t++){
        gru_phase(tid, b0,
                  HIST + (size_t)t*BATCH*HD, HB[p], PENC, ebih, ebhh,
                  HF[p], HF[p^1], HB[p^1], ENC_OUT + (size_t)t*BATCH*HD, As);
        p ^= 1;
    }

    // =================== decoder ===================
    for (int t = 0; t < LFWD; t++){
        const bf16_t* hbf = HB[p];
        const bf16_t* fxt = FXB + (size_t)t*BATCH*KIN;

        // ---- stage [h|fx] (R2 e/attn staging) ----
        for (int i = tid; i < 576; i += 512){
            int r = i/36, c = i - r*36;
            const bf16_t* src = (c<32)? (hbf + (size_t)(b0+r)*HD + c*8)
                                      : (fxt + (size_t)(b0+r)*KIN + (c-32)*8);
            *(uint4*)&As[r][c*8] = *(const uint4*)src;
        }
        __syncthreads();
        const char* arow = (const char*)&As[lane&15][(lane>>4)*8];

        // ---- e tiles (R2 e_kernel body) -> EBUF ----
        {
            const char* bp = (const char*)PE;
            int kt0 = (t==0)? 8 : 0;
            const float* eb = (t==0)? DEMBB : EBIAS;
            #pragma unroll
            for (int half=0; half<2; half++){
                int nt = wave + 8*half;
                f32x4 c = {0,0,0,0};
                for (int kt=kt0; kt<9; kt++){
                    bf16x8 a = *(const bf16x8*)(arow + kt*64);
                    bf16x8 b = *(const bf16x8*)(bp + (size_t)((nt*9+kt)<<10) + loff);
                    c = __builtin_amdgcn_mfma_f32_16x16x32_bf16(a, b, c, 0,0,0);
                }
                int n = (nt<<4) + (lane&15);
                float bb = eb[n];
                #pragma unroll
                for (int q=0;q<4;q++){
                    int b = b0 + ((lane>>4)<<2) + q;
                    EBUF[(size_t)b*HD + n] = f2bf(c[q] + bb);
                }
            }
        }
        // ---- logits tiles (R2 attn_kernel body) -> lg ----
        {
            const char* blp = (const char*)((t==0)? PBL0 : PBL);
            const float* lbp = (t==0)? LB0g : LBg;
            for (int nt = wave; nt < 5; nt += 8){
                f32x4 c = {0,0,0,0};
                #pragma unroll
                for (int kt=0; kt<9; kt++){
                    bf16x8 a = *(const bf16x8*)(arow + kt*64);
                    bf16x8 b = *(const bf16x8*)(blp + (size_t)((nt*9+kt)<<10) + loff);
                    c = __builtin_amdgcn_mfma_f32_16x16x32_bf16(a, b, c, 0,0,0);
                }
                int mcol = (nt<<4) + (lane&15);
                float bb = lbp[mcol];
                #pragma unroll
                for (int q=0;q<4;q++) lg[((lane>>4)<<2)+q][mcol] = c[q] + bb;
            }
        }
        __syncthreads();

        // ---- softmax (R2 verbatim, tid<256 active, uniform barriers) ----
        {
            int r = tid>>4, l2 = tid&15;
            if (tid < 256){
                float vmax = -1e30f;
                for (int m=l2; m<80; m+=16) vmax = fmaxf(vmax, lg[r][m]);
                red[r][l2] = vmax;
            }
            __syncthreads();
            if (tid < 256 && l2==0){
                float v = red[r][0];
                #pragma unroll
                for (int i=1;i<16;i++) v = fmaxf(v, red[r][i]);
                rmax[r] = v;
            }
            __syncthreads();
            if (tid < 256){
                float vm = rmax[r], ps = 0.f;
                for (int m=l2; m<80; m+=16){ float v=__expf(lg[r][m]-vm); lg[r][m]=v; ps+=v; }
                red[r][l2] = ps;
            }
            __syncthreads();
            if (tid < 256 && l2==0){
                float s = 0.f;
                #pragma unroll
                for (int i=0;i<16;i++) s += red[r][i];
                rsum[r] = s;
            }
            __syncthreads();
            if (tid < 256){
                float inv = 1.0f/rsum[r];
                for (int m=l2; m<60; m+=16) awl[r][m] = lg[r][m]*inv;
            }
            __syncthreads();
        }

        // ---- ctx: global ENC_OUT ([m][B][H]) x awl -> CTXB ----
        {
            int cr2 = tid>>5, cc2 = (tid&31)*8;
            float acc[8] = {0,0,0,0,0,0,0,0};
            const bf16_t* ep = ENC_OUT + (size_t)(b0+cr2)*HD + cc2;
            for (int m=0; m<LPRE; m++){
                bf16x8 ev = *(const bf16x8*)(ep + (size_t)m*BATCH*HD);
                float a = awl[cr2][m];
                #pragma unroll
                for (int k=0;k<8;k++) acc[k] += a * bf2f(((const bf16_t*)&ev)[k]);
            }
            bf16_t tmp[8];
            #pragma unroll
            for (int k=0;k<8;k++) tmp[k] = f2bf(acc[k]);
            *(uint4*)(CTXB + (size_t)(b0+cr2)*HD + cc2) = *(const uint4*)tmp;
        }
        __syncthreads();

        // ---- comb (R2 comb_kernel body): [e|ctx]@Bcmb -> GBUF ----
        {
            for (int i = tid; i < 1024; i += 512){
                int r = i>>6, c = i&63;
                const bf16_t* src = (c<32)? (EBUF + (size_t)(b0+r)*HD + c*8)
                                          : (CTXB + (size_t)(b0+r)*HD + (c-32)*8);
                *(uint4*)&As[r][c*8] = *(const uint4*)src;
            }
            __syncthreads();
            const char* bp = (const char*)PCMB;
            const char* arw = (const char*)&As[lane&15][(lane>>4)*8];
            #pragma unroll
            for (int half=0; half<2; half++){
                int nt = wave + 8*half;
                f32x4 c = {0,0,0,0};
                #pragma unroll
                for (int kt=0; kt<16; kt++){
                    bf16x8 a = *(const bf16x8*)(arw + kt*64);
                    bf16x8 b = *(const bf16x8*)(bp + (size_t)(((nt<<4)+kt)<<10) + loff);
                    c = __builtin_amdgcn_mfma_f32_16x16x32_bf16(a, b, c, 0,0,0);
                }
                int n = (nt<<4) + (lane&15);
                float bb = CBg[n];
                #pragma unroll
                for (int q=0;q<4;q++){
                    int b = b0 + ((lane>>4)<<2) + q;
                    GBUF[(size_t)b*HD + n] = f2bf(tanhf(c[q] + bb));
                }
            }
            __syncthreads();
        }

        // ---- decoder GRU (R2 gru_step body); h-hist tile t -> HIST ----
        gru_phase(tid, b0,
                  GBUF, HB[p], PDEC, dbih, dbhh,
                  HF[p], HF[p^1], HB[p^1], HIST + (size_t)t*BATCH*HD, As);
        p ^= 1;
    }
}

// ---------------------------------------------------------------------------
// ys[t] = h_hist[t]@outW^T + outB (R2 verbatim). grid (64,80)x256.
// ---------------------------------------------------------------------------
__global__ __launch_bounds__(256) void final_out(
    const bf16_t* __restrict__ hist, const float* __restrict__ outW,
    const float* __restrict__ outB, float* __restrict__ ys)
{
    __shared__ float hs[16][256];
    __shared__ float ow[16*260];
    __shared__ float ob[16];
    int tid = threadIdx.x, b0 = blockIdx.x*16, t = blockIdx.y;
    for (int i = tid; i < 4096; i += 256){
        int o = i>>8, k = i&255;
        ow[o*260+k] = outW[(size_t)o*HD + k];
    }
    if (tid < 16) ob[tid] = outB[tid];
    for (int i = tid; i < 4096; i += 256){
        int r = i>>8, k = i&255;
        hs[r][k] = bf2f(hist[((size_t)t*BATCH + b0+r)*HD + k]);
    }
    __syncthreads();
    int r = tid>>4, o = tid&15;
    float acc = ob[o];
    const float* w = &ow[o*260];
    for (int k=0;k<256;k++) acc += hs[r][k]*w[k];
    ys[((size_t)t*BATCH + b0+r)*KOUT + o] = acc;
}

// ---------------------------------------------------------------------------
extern "C" void kernel_launch(void* const* d_in, const int* in_sizes, int n_in,
                              void* d_out, int out_size, void* d_ws, size_t ws_size,
                              hipStream_t stream) {
    const float* pre_x    = (const float*)d_in[0];
    const float* pre_y    = (const float*)d_in[1];
    const float* fwd_x    = (const float*)d_in[2];
    const float* enc_embW = (const float*)d_in[3];
    const float* enc_embB = (const float*)d_in[4];
    const float* enc_Wih  = (const float*)d_in[5];
    const float* enc_Whh  = (const float*)d_in[6];
    const float* enc_bih  = (const float*)d_in[7];
    const float* enc_bhh  = (const float*)d_in[8];
    const float* dec_embW = (const float*)d_in[9];
    const float* dec_embB = (const float*)d_in[10];
    const float* attn_W   = (const float*)d_in[11];
    const float* attn_b   = (const float*)d_in[12];
    const float* comb_W   = (const float*)d_in[13];
    const float* comb_b   = (const float*)d_in[14];
    const float* dec_Wih  = (const float*)d_in[15];
    const float* dec_Whh  = (const float*)d_in[16];
    const float* dec_bih  = (const float*)d_in[17];
    const float* dec_bhh  = (const float*)d_in[18];
    const float* out_W    = (const float*)d_in[19];
    const float* out_b    = (const float*)d_in[20];
    float* out = (float*)d_out;

    char* ws = (char*)d_ws;
    size_t o = 0;
    auto alloc = [&](size_t bytes)->char*{
        char* p = ws + o; o = (o + bytes + 255) & ~(size_t)255; return p;
    };
    bf16_t* HIST    = (bf16_t*)alloc((size_t)LFWD*BATCH*HD*2);   // 41.9 MB: emb (t<60) then h-hist
    bf16_t* ENC_OUT = (bf16_t*)alloc((size_t)LPRE*BATCH*HD*2);   // 31.5 MB
    bf16_t* FXB     = (bf16_t*)alloc((size_t)LFWD*BATCH*KIN*2);
    float*  HF0     = (float*) alloc((size_t)BATCH*HD*4);
    float*  HF1     = (float*) alloc((size_t)BATCH*HD*4);
    bf16_t* HB0     = (bf16_t*)alloc((size_t)BATCH*HD*2);
    bf16_t* HB1     = (bf16_t*)alloc((size_t)BATCH*HD*2);
    bf16_t* EBUF    = (bf16_t*)alloc((size_t)BATCH*HD*2);
    bf16_t* CTXB    = (bf16_t*)alloc((size_t)BATCH*HD*2);
    bf16_t* GBUF    = (bf16_t*)alloc((size_t)BATCH*HD*2);
    float*  WFUSE   = (float*) alloc((size_t)256*256*4);
    float*  EBIAS   = (float*) alloc(256*4);
    float*  LB      = (float*) alloc(80*4);
    float*  LB0     = (float*) alloc(80*4);
    bf16_t* PACK_ENC = (bf16_t*)alloc(786432);
    bf16_t* PACK_DEC = (bf16_t*)alloc(786432);
    bf16_t* PACK_CMB = (bf16_t*)alloc(262144);
    bf16_t* PACK_E   = (bf16_t*)alloc(147456);
    bf16_t* PACK_BL  = (bf16_t*)alloc(46080);
    bf16_t* PACK_BL0 = (bf16_t*)alloc(46080);

    hipMemsetAsync(HF0, 0, (size_t)BATCH*HD*4, stream);
    hipMemsetAsync(HB0, 0, (size_t)BATCH*HD*2, stream);

    dim3 blk(256);
    // ---- prep (all state-independent, R2 verbatim) ----
    emb_kernel<<<dim3(64,60), blk, 0, stream>>>(pre_x, pre_y, enc_embW, enc_embB, HIST);
    fxconv<<<dim3(1280), blk, 0, stream>>>(fwd_x, FXB);
    pack_gru<<<dim3(192), blk, 0, stream>>>(enc_Wih, enc_Whh, PACK_ENC);
    pack_gru<<<dim3(192), blk, 0, stream>>>(dec_Wih, dec_Whh, PACK_DEC);
    pack_B512<<<dim3(64), blk, 0, stream>>>(comb_W, PACK_CMB);
    wfuse_kernel<<<dim3(257), blk, 0, stream>>>(dec_embW, dec_embB, out_W, out_b, WFUSE, EBIAS);
    pack_e<<<dim3(36), blk, 0, stream>>>(WFUSE, dec_embW, PACK_E);
    pack_logits<<<dim3(24), blk, 0, stream>>>(WFUSE, dec_embW, attn_W, attn_b, dec_embB,
                                              EBIAS, PACK_BL, PACK_BL0, LB, LB0);

    // ---- the whole recurrence in ONE launch ----
    seq_kernel<<<dim3(64), dim3(512), 0, stream>>>(
        FXB, PACK_ENC, PACK_DEC, PACK_CMB, PACK_E, PACK_BL, PACK_BL0,
        enc_bih, enc_bhh, dec_bih, dec_bhh,
        EBIAS, dec_embB, LB, LB0, comb_b,
        HIST, ENC_OUT, HF0, HF1, HB0, HB1, EBUF, CTXB, GBUF);

    // ---- outputs ----
    final_out<<<dim3(64,80), blk, 0, stream>>>(HIST, out_W, out_b, out);
}